// Round 11
// baseline (251.561 us; speedup 1.0000x reference)
//
#include <hip/hip_runtime.h>
#include <math.h>

#define NB  1024
#define NN  256
#define NF  4
#define NK  3
#define BIG 32
#define HID 2
#define BN_EPS 1e-5f
#define FLT_BIG 3.402823466e38f

typedef float f32x16 __attribute__((ext_vector_type(16)));
typedef float f32x4v __attribute__((ext_vector_type(4)));

static __device__ __forceinline__ f32x16 splat16(float s) {
    f32x16 v;
#pragma unroll
    for (int k = 0; k < 16; ++k) v[k] = s;
    return v;
}
static __device__ __forceinline__ f32x16 relu16(f32x16 v) {
    return __builtin_elementwise_max(v, splat16(0.0f));
}
static __device__ __forceinline__ f32x16 ldw16(const float* __restrict__ p) {
    return *(const f32x16*)p;   // uniform addr -> s_load_dwordx16
}
static __device__ __forceinline__ f32x4v ldw4(const float* __restrict__ p) {
    return *(const f32x4v*)p;
}
static __device__ __forceinline__ f32x4v splat4(float s) {
    f32x4v v; v[0] = s; v[1] = s; v[2] = s; v[3] = s; return v;
}

#define ROW1(s, base, Aa, Ab) { \
    f32x16 w0_ = ldw16(base); f32x16 w1_ = ldw16((base) + 16); \
    f32x16 sv_ = splat16(s); Aa += sv_ * w0_; Ab += sv_ * w1_; }

#define ROW2(s0, s1, base, A0a, A0b, A1a, A1b) { \
    f32x16 w0_ = ldw16(base); f32x16 w1_ = ldw16((base) + 16); \
    A0a += splat16(s0) * w0_; A0b += splat16(s0) * w1_; \
    A1a += splat16(s1) * w0_; A1b += splat16(s1) * w1_; }

#define L2J(wbase, bbase, COFF, IN0a, IN0b, IN1a, IN1b, Q0, Q1) \
    f32x16 Q0 = ldw16((bbase) + (COFF)); f32x16 Q1 = Q0; \
    _Pragma("unroll") \
    for (int i_ = 0; i_ < 16; i_++) { \
        f32x16 w_ = ldw16((wbase) + i_ * BIG + (COFF)); \
        Q0 += splat16(IN0a[i_]) * w_; Q1 += splat16(IN1a[i_]) * w_; } \
    _Pragma("unroll") \
    for (int i_ = 0; i_ < 16; i_++) { \
        f32x16 w_ = ldw16((wbase) + (16 + i_) * BIG + (COFF)); \
        Q0 += splat16(IN0b[i_]) * w_; Q1 += splat16(IN1b[i_]) * w_; } \
    Q0 = relu16(Q0); Q1 = relu16(Q1);

#define L2S(wbase, bbase, COFF, INa, INb, Q) \
    f32x16 Q = ldw16((bbase) + (COFF)); \
    _Pragma("unroll") \
    for (int i_ = 0; i_ < 16; i_++) { \
        f32x16 w_ = ldw16((wbase) + i_ * BIG + (COFF)); \
        Q += splat16(INa[i_]) * w_; } \
    _Pragma("unroll") \
    for (int i_ = 0; i_ < 16; i_++) { \
        f32x16 w_ = ldw16((wbase) + (16 + i_) * BIG + (COFF)); \
        Q += splat16(INb[i_]) * w_; } \
    Q = relu16(Q);

#define L3EJ(COFF, Q0, Q1) { \
    f32x16 wA_ = ldw16(ew3 + (COFF) * 2); \
    f32x16 wB_ = ldw16(ew3 + (COFF) * 2 + 16); \
    _Pragma("unroll") \
    for (int i_ = 0; i_ < 8; i_++) { \
        o0e0 += Q0[i_] * wA_[2 * i_]; o1e0 += Q0[i_] * wA_[2 * i_ + 1]; \
        o0e1 += Q1[i_] * wA_[2 * i_]; o1e1 += Q1[i_] * wA_[2 * i_ + 1]; } \
    _Pragma("unroll") \
    for (int i_ = 0; i_ < 8; i_++) { \
        o0e0 += Q0[8 + i_] * wB_[2 * i_]; o1e0 += Q0[8 + i_] * wB_[2 * i_ + 1]; \
        o0e1 += Q1[8 + i_] * wB_[2 * i_]; o1e1 += Q1[8 + i_] * wB_[2 * i_ + 1]; } }

#define L3ES(COFF, Q) { \
    f32x16 wA_ = ldw16(ew3 + (COFF) * 2); \
    f32x16 wB_ = ldw16(ew3 + (COFF) * 2 + 16); \
    _Pragma("unroll") \
    for (int i_ = 0; i_ < 8; i_++) { \
        o0e2 += Q[i_] * wA_[2 * i_]; o1e2 += Q[i_] * wA_[2 * i_ + 1]; } \
    _Pragma("unroll") \
    for (int i_ = 0; i_ < 8; i_++) { \
        o0e2 += Q[8 + i_] * wB_[2 * i_]; o1e2 += Q[8 + i_] * wB_[2 * i_ + 1]; } }

#define L3DJ(COFF, Q0, Q1) { \
    _Pragma("unroll") \
    for (int i_ = 0; i_ < 16; i_++) { \
        f32x4v w_ = ldw4(dw3 + ((COFF) + i_) * 4); \
        ove0 += splat4(Q0[i_]) * w_; ove1 += splat4(Q1[i_]) * w_; } }

#define L3DS(COFF, Q) { \
    _Pragma("unroll") \
    for (int i_ = 0; i_ < 16; i_++) { \
        f32x4v w_ = ldw4(dw3 + ((COFF) + i_) * 4); \
        ove2 += splat4(Q[i_]) * w_; } }

// top-3 streaming insert: strict <, fmed3 distances, cndmask indices.
#define KNN_UPDATE(d, m) { \
    bool c0 = (d) < d0, c1 = (d) < d1, c2 = (d) < d2; \
    i2 = c1 ? i1 : (c2 ? (m) : i2); \
    i1 = c0 ? i0 : (c1 ? (m) : i1); \
    i0 = c0 ? (m) : i0; \
    d2 = __builtin_amdgcn_fmed3f((d), d1, d2); \
    d1 = __builtin_amdgcn_fmed3f((d), d0, d1); \
    d0 = fminf((d), d0); }

// ---------------------------------------------------------------------------
__global__ void k_zero_ws(double* ws) {
    if (threadIdx.x < 8) ws[threadIdx.x] = 0.0;
}

__global__ __launch_bounds__(256) void k_bn_reduce(const float4* __restrict__ x,
                                                   double* __restrict__ ws) {
    int tid = blockIdx.x * 256 + threadIdx.x;
    double s[8] = {0, 0, 0, 0, 0, 0, 0, 0};
    for (int r = tid; r < NB * NN; r += 256 * 256) {
        float4 v = x[r];
        s[0] += v.x; s[1] += v.y; s[2] += v.z; s[3] += v.w;
        s[4] += (double)v.x * v.x; s[5] += (double)v.y * v.y;
        s[6] += (double)v.z * v.z; s[7] += (double)v.w * v.w;
    }
#pragma unroll
    for (int off = 32; off > 0; off >>= 1) {
#pragma unroll
        for (int i = 0; i < 8; i++) s[i] += __shfl_down(s[i], off);
    }
    __shared__ double red[4][8];
    int w = threadIdx.x >> 6, lane = threadIdx.x & 63;
    if (lane == 0) {
#pragma unroll
        for (int i = 0; i < 8; i++) red[w][i] = s[i];
    }
    __syncthreads();
    if (threadIdx.x == 0) {
#pragma unroll
        for (int i = 0; i < 8; i++) {
            double t = red[0][i] + red[1][i] + red[2][i] + red[3][i];
            atomicAdd(&ws[i], t);
        }
    }
}

// ---------------------------------------------------------------------------
// Fused kernel, 2 threads per node (512 threads / graph).
// half A (tid<256): kNN over m in [0,128), merge with B's top-3 (stable),
//                   joint MLP for edges (i0,i1), final combine + store.
// half B (tid>=256): kNN over m in [128,256), publish top-3, solo MLP for i2.
// __launch_bounds__(512,2): <=256-VGPR budget so the ~130-reg live set stays
// in registers (round-10's (512,4) forced 64 VGPRs -> ~95 MB spill traffic).
// ---------------------------------------------------------------------------
__global__ __launch_bounds__(512, 2) void k_edgenet(
    const float*  __restrict__ x,
    const float*  __restrict__ gmm, const float* __restrict__ bta,
    const float*  __restrict__ ew1, const float* __restrict__ eb1,
    const float*  __restrict__ ew2, const float* __restrict__ eb2,
    const float*  __restrict__ ew3, const float* __restrict__ eb3,
    const float*  __restrict__ dw1, const float* __restrict__ db1,
    const float*  __restrict__ dw2, const float* __restrict__ db2,
    const float*  __restrict__ dw3, const float* __restrict__ db3,
    const double* __restrict__ bnstat,
    float*        __restrict__ out)
{
    __shared__ float4 s_h4[NN];
    __shared__ float  s_sq[NN];
    __shared__ float2 s_he2[NN];
    __shared__ float  s_sq2[NN];
    __shared__ float  s_bd[NN][4];   // B's top-3 distances
    __shared__ int    s_bi[NN][4];   // B's top-3 indices
    __shared__ int    s_i2[NN];      // final 3rd neighbor (A -> B)
    __shared__ float4 s_part[NN];    // B's solo-edge partial

    const int tid  = threadIdx.x;
    const int n    = tid & (NN - 1);
    const int half = tid >> 8;       // wave-uniform
    const int b    = blockIdx.x;

    // BN parameters (uniform)
    const double cnt = (double)(NB * NN);
    float mu[NF], rstd[NF];
#pragma unroll
    for (int f = 0; f < NF; f++) {
        double m   = bnstat[f] / cnt;
        double var = bnstat[4 + f] / cnt - m * m;
        mu[f]   = (float)m;
        rstd[f] = 1.0f / sqrtf((float)var + BN_EPS);
    }

    if (half == 0) {
        float4 xv = ((const float4*)x)[b * NN + n];
        float t0 = (xv.x - mu[0]) * rstd[0] * gmm[0] + bta[0];
        float t1 = (xv.y - mu[1]) * rstd[1] * gmm[1] + bta[1];
        float t2 = (xv.z - mu[2]) * rstd[2] * gmm[2] + bta[2];
        float t3 = (xv.w - mu[3]) * rstd[3] * gmm[3] + bta[3];
        s_h4[n] = make_float4(t0, t1, t2, t3);
        s_sq[n] = t0 * t0 + t1 * t1 + t2 * t2 + t3 * t3;
    }
    __syncthreads();

    float4 hv = s_h4[n];
    float h0 = hv.x, h1 = hv.y, h2 = hv.z, h3 = hv.w;
    float sq = s_sq[n];

    // ---------------- encoder kNN: half-scan -------------------------------
    float d0 = FLT_BIG, d1 = FLT_BIG, d2 = FLT_BIG;
    int   i0 = 0, i1 = 0, i2 = 0;
    {
        const int mbeg = half << 7, mend = mbeg + 128;
        for (int m = mbeg; m < mend; ++m) {
            float4 a = s_h4[m];
            float dot = h0 * a.x + h1 * a.y + h2 * a.z + h3 * a.w;
            float dd = (sq + s_sq[m]) - 2.0f * dot;
            KNN_UPDATE(dd, m);
        }
    }
    if (half == 1) {
        s_bd[n][0] = d0; s_bd[n][1] = d1; s_bd[n][2] = d2;
        s_bi[n][0] = i0; s_bi[n][1] = i1; s_bi[n][2] = i2;
    }
    __syncthreads();
    if (half == 0) {
#pragma unroll
        for (int t = 0; t < 3; ++t) {
            float dm = s_bd[n][t]; int im = s_bi[n][t];
            KNN_UPDATE(dm, im);
        }
        s_i2[n] = i2;
    }
    __syncthreads();

    // ---------------- encoder MLP ------------------------------------------
    float msA0 = 0.0f, msA1 = 0.0f;
    if (half == 0) {
        // edges (i0,i1) joint
        f32x16 ca = ldw16(eb1), cb = ldw16(eb1 + 16);
        ROW1(h0, ew1 + 0 * BIG, ca, cb);
        ROW1(h1, ew1 + 1 * BIG, ca, cb);
        ROW1(h2, ew1 + 2 * BIG, ca, cb);
        ROW1(h3, ew1 + 3 * BIG, ca, cb);

        float4 a0v = s_h4[i0], a1v = s_h4[i1];
        float p00 = a0v.x - h0, p01 = a0v.y - h1;
        float p02 = a0v.z - h2, p03 = a0v.w - h3;
        float p10 = a1v.x - h0, p11 = a1v.y - h1;
        float p12 = a1v.z - h2, p13 = a1v.w - h3;

        f32x16 A0a = ca, A0b = cb, A1a = ca, A1b = cb;
        ROW2(p00, p10, ew1 + 4 * BIG, A0a, A0b, A1a, A1b);
        ROW2(p01, p11, ew1 + 5 * BIG, A0a, A0b, A1a, A1b);
        ROW2(p02, p12, ew1 + 6 * BIG, A0a, A0b, A1a, A1b);
        ROW2(p03, p13, ew1 + 7 * BIG, A0a, A0b, A1a, A1b);
        A0a = relu16(A0a); A0b = relu16(A0b);
        A1a = relu16(A1a); A1b = relu16(A1b);

        float o0e0 = eb3[0], o1e0 = eb3[1];
        float o0e1 = eb3[0], o1e1 = eb3[1];
        { L2J(ew2, eb2, 0,  A0a, A0b, A1a, A1b, QA0, QA1); L3EJ(0,  QA0, QA1); }
        { L2J(ew2, eb2, 16, A0a, A0b, A1a, A1b, QB0, QB1); L3EJ(16, QB0, QB1); }
        msA0 = fmaxf(o0e0, 0.0f) + fmaxf(o0e1, 0.0f);
        msA1 = fmaxf(o1e0, 0.0f) + fmaxf(o1e1, 0.0f);
    } else {
        // edge i2 solo
        int j2 = s_i2[n];
        f32x16 Aa = ldw16(eb1), Ab = ldw16(eb1 + 16);
        ROW1(h0, ew1 + 0 * BIG, Aa, Ab);
        ROW1(h1, ew1 + 1 * BIG, Aa, Ab);
        ROW1(h2, ew1 + 2 * BIG, Aa, Ab);
        ROW1(h3, ew1 + 3 * BIG, Aa, Ab);
        float4 a2v = s_h4[j2];
        float p20 = a2v.x - h0, p21 = a2v.y - h1;
        float p22 = a2v.z - h2, p23 = a2v.w - h3;
        ROW1(p20, ew1 + 4 * BIG, Aa, Ab);
        ROW1(p21, ew1 + 5 * BIG, Aa, Ab);
        ROW1(p22, ew1 + 6 * BIG, Aa, Ab);
        ROW1(p23, ew1 + 7 * BIG, Aa, Ab);
        Aa = relu16(Aa); Ab = relu16(Ab);

        float o0e2 = eb3[0], o1e2 = eb3[1];
        { L2S(ew2, eb2, 0,  Aa, Ab, QS0); L3ES(0,  QS0); }
        { L2S(ew2, eb2, 16, Aa, Ab, QS1); L3ES(16, QS1); }
        s_part[n].x = fmaxf(o0e2, 0.0f);
        s_part[n].y = fmaxf(o1e2, 0.0f);
    }
    __syncthreads();

    if (half == 0) {
        float ms0 = msA0 + s_part[n].x;   // ((r0+r1)+r2) — round-8 order
        float ms1 = msA1 + s_part[n].y;
        float he0 = ms0 / 3.0f, he1 = ms1 / 3.0f;
        s_he2[n] = make_float2(he0, he1);
        s_sq2[n] = he0 * he0 + he1 * he1;
    }
    __syncthreads();

    float2 hev = s_he2[n];
    float he0 = hev.x, he1 = hev.y;
    float sqe = s_sq2[n];

    // ---------------- decoder kNN: half-scan -------------------------------
    d0 = FLT_BIG; d1 = FLT_BIG; d2 = FLT_BIG;
    i0 = 0; i1 = 0; i2 = 0;
    {
        const int mbeg = half << 7, mend = mbeg + 128;
        for (int m = mbeg; m < mend; ++m) {
            float2 a = s_he2[m];
            float dot = he0 * a.x + he1 * a.y;
            float dd = (sqe + s_sq2[m]) - 2.0f * dot;
            KNN_UPDATE(dd, m);
        }
    }
    if (half == 1) {
        s_bd[n][0] = d0; s_bd[n][1] = d1; s_bd[n][2] = d2;
        s_bi[n][0] = i0; s_bi[n][1] = i1; s_bi[n][2] = i2;
    }
    __syncthreads();
    if (half == 0) {
#pragma unroll
        for (int t = 0; t < 3; ++t) {
            float dm = s_bd[n][t]; int im = s_bi[n][t];
            KNN_UPDATE(dm, im);
        }
        s_i2[n] = i2;
    }
    __syncthreads();

    // ---------------- decoder MLP ------------------------------------------
    f32x4v ovA = {0.0f, 0.0f, 0.0f, 0.0f};
    if (half == 0) {
        f32x16 ca = ldw16(db1), cb = ldw16(db1 + 16);
        ROW1(he0, dw1 + 0 * BIG, ca, cb);
        ROW1(he1, dw1 + 1 * BIG, ca, cb);

        float2 a0v = s_he2[i0], a1v = s_he2[i1];
        float p00 = a0v.x - he0, p01 = a0v.y - he1;
        float p10 = a1v.x - he0, p11 = a1v.y - he1;

        f32x16 B0a = ca, B0b = cb, B1a = ca, B1b = cb;
        ROW2(p00, p10, dw1 + 2 * BIG, B0a, B0b, B1a, B1b);
        ROW2(p01, p11, dw1 + 3 * BIG, B0a, B0b, B1a, B1b);
        B0a = relu16(B0a); B0b = relu16(B0b);
        B1a = relu16(B1a); B1b = relu16(B1b);

        f32x4v ove0 = ldw4(db3), ove1 = ldw4(db3);
        { L2J(dw2, db2, 0,  B0a, B0b, B1a, B1b, QD0, QD1); L3DJ(0,  QD0, QD1); }
        { L2J(dw2, db2, 16, B0a, B0b, B1a, B1b, QE0, QE1); L3DJ(16, QE0, QE1); }
        ovA = ove0 + ove1;
    } else {
        int j2 = s_i2[n];
        f32x16 Ba = ldw16(db1), Bb = ldw16(db1 + 16);
        ROW1(he0, dw1 + 0 * BIG, Ba, Bb);
        ROW1(he1, dw1 + 1 * BIG, Ba, Bb);
        float2 a2v = s_he2[j2];
        float p20 = a2v.x - he0, p21 = a2v.y - he1;
        ROW1(p20, dw1 + 2 * BIG, Ba, Bb);
        ROW1(p21, dw1 + 3 * BIG, Ba, Bb);
        Ba = relu16(Ba); Bb = relu16(Bb);

        f32x4v ove2 = ldw4(db3);
        { L2S(dw2, db2, 0,  Ba, Bb, QF0); L3DS(0,  QF0); }
        { L2S(dw2, db2, 16, Ba, Bb, QF1); L3DS(16, QF1); }
        s_part[n] = make_float4(ove2[0], ove2[1], ove2[2], ove2[3]);
    }
    __syncthreads();

    if (half == 0) {
        float4 t = s_part[n];
        f32x4v ovB; ovB[0] = t.x; ovB[1] = t.y; ovB[2] = t.z; ovB[3] = t.w;
        f32x4v osum = ovA + ovB;              // (ove0+ove1)+ove2 — round-8 order
        float4 ov;
        ov.x = osum[0] / 3.0f; ov.y = osum[1] / 3.0f;
        ov.z = osum[2] / 3.0f; ov.w = osum[3] / 3.0f;
        ((float4*)out)[b * NN + n] = ov;
    }
}

// ---------------------------------------------------------------------------
extern "C" void kernel_launch(void* const* d_in, const int* in_sizes, int n_in,
                              void* d_out, int out_size, void* d_ws, size_t ws_size,
                              hipStream_t stream) {
    const float* x   = (const float*)d_in[0];
    const float* gmm = (const float*)d_in[1];
    const float* bta = (const float*)d_in[2];
    const float* ew1 = (const float*)d_in[3];
    const float* eb1 = (const float*)d_in[4];
    const float* ew2 = (const float*)d_in[5];
    const float* eb2 = (const float*)d_in[6];
    const float* ew3 = (const float*)d_in[7];
    const float* eb3 = (const float*)d_in[8];
    const float* dw1 = (const float*)d_in[9];
    const float* db1 = (const float*)d_in[10];
    const float* dw2 = (const float*)d_in[11];
    const float* db2 = (const float*)d_in[12];
    const float* dw3 = (const float*)d_in[13];
    const float* db3 = (const float*)d_in[14];
    double* ws = (double*)d_ws;
    float* out = (float*)d_out;

    hipLaunchKernelGGL(k_zero_ws, dim3(1), dim3(64), 0, stream, ws);
    hipLaunchKernelGGL(k_bn_reduce, dim3(256), dim3(256), 0, stream,
                       (const float4*)x, ws);
    hipLaunchKernelGGL(k_edgenet, dim3(NB), dim3(512), 0, stream,
                       x, gmm, bta, ew1, eb1, ew2, eb2, ew3, eb3,
                       dw1, db1, dw2, db2, dw3, db3, ws, out);
}

// Round 12
// 234.613 us; speedup vs baseline: 1.0722x; 1.0722x over previous
//
#include <hip/hip_runtime.h>
#include <math.h>

#define NB  1024
#define NN  256
#define NF  4
#define NK  3
#define BIG 32
#define HID 2
#define BN_EPS 1e-5f
#define FLT_BIG 3.402823466e38f

typedef float f32x16 __attribute__((ext_vector_type(16)));
typedef float f32x4v __attribute__((ext_vector_type(4)));

static __device__ __forceinline__ f32x16 splat16(float s) {
    f32x16 v;
#pragma unroll
    for (int k = 0; k < 16; ++k) v[k] = s;
    return v;
}
static __device__ __forceinline__ f32x16 relu16(f32x16 v) {
    return __builtin_elementwise_max(v, splat16(0.0f));
}
static __device__ __forceinline__ f32x16 ldw16(const float* __restrict__ p) {
    return *(const f32x16*)p;   // uniform addr -> s_load_dwordx16
}
static __device__ __forceinline__ f32x4v ldw4(const float* __restrict__ p) {
    return *(const f32x4v*)p;
}
static __device__ __forceinline__ f32x4v splat4(float s) {
    f32x4v v; v[0] = s; v[1] = s; v[2] = s; v[3] = s; return v;
}

#define ROW1(s, base, Aa, Ab) { \
    f32x16 w0_ = ldw16(base); f32x16 w1_ = ldw16((base) + 16); \
    f32x16 sv_ = splat16(s); Aa += sv_ * w0_; Ab += sv_ * w1_; }

#define L2S(wbase, bbase, COFF, INa, INb, Q) \
    f32x16 Q = ldw16((bbase) + (COFF)); \
    _Pragma("unroll") \
    for (int i_ = 0; i_ < 16; i_++) { \
        f32x16 w_ = ldw16((wbase) + i_ * BIG + (COFF)); \
        Q += splat16(INa[i_]) * w_; } \
    _Pragma("unroll") \
    for (int i_ = 0; i_ < 16; i_++) { \
        f32x16 w_ = ldw16((wbase) + (16 + i_) * BIG + (COFF)); \
        Q += splat16(INb[i_]) * w_; } \
    Q = relu16(Q);

#define L3ES(COFF, Q) { \
    f32x16 wA_ = ldw16(ew3 + (COFF) * 2); \
    f32x16 wB_ = ldw16(ew3 + (COFF) * 2 + 16); \
    _Pragma("unroll") \
    for (int i_ = 0; i_ < 8; i_++) { \
        o0e2 += Q[i_] * wA_[2 * i_]; o1e2 += Q[i_] * wA_[2 * i_ + 1]; } \
    _Pragma("unroll") \
    for (int i_ = 0; i_ < 8; i_++) { \
        o0e2 += Q[8 + i_] * wB_[2 * i_]; o1e2 += Q[8 + i_] * wB_[2 * i_ + 1]; } }

#define L3DS(COFF, Q) { \
    _Pragma("unroll") \
    for (int i_ = 0; i_ < 16; i_++) { \
        f32x4v w_ = ldw4(dw3 + ((COFF) + i_) * 4); \
        ove2 += splat4(Q[i_]) * w_; } }

// top-3 streaming insert: strict <, fmed3 distances, cndmask indices.
#define KNN_UPDATE(d, m) { \
    bool c0 = (d) < d0, c1 = (d) < d1, c2 = (d) < d2; \
    i2 = c1 ? i1 : (c2 ? (m) : i2); \
    i1 = c0 ? i0 : (c1 ? (m) : i1); \
    i0 = c0 ? (m) : i0; \
    d2 = __builtin_amdgcn_fmed3f((d), d1, d2); \
    d1 = __builtin_amdgcn_fmed3f((d), d0, d1); \
    d0 = fminf((d), d0); }

// ---------------------------------------------------------------------------
__global__ void k_zero_ws(double* ws) {
    if (threadIdx.x < 8) ws[threadIdx.x] = 0.0;
}

__global__ __launch_bounds__(256) void k_bn_reduce(const float4* __restrict__ x,
                                                   double* __restrict__ ws) {
    int tid = blockIdx.x * 256 + threadIdx.x;
    double s[8] = {0, 0, 0, 0, 0, 0, 0, 0};
    for (int r = tid; r < NB * NN; r += 256 * 256) {
        float4 v = x[r];
        s[0] += v.x; s[1] += v.y; s[2] += v.z; s[3] += v.w;
        s[4] += (double)v.x * v.x; s[5] += (double)v.y * v.y;
        s[6] += (double)v.z * v.z; s[7] += (double)v.w * v.w;
    }
#pragma unroll
    for (int off = 32; off > 0; off >>= 1) {
#pragma unroll
        for (int i = 0; i < 8; i++) s[i] += __shfl_down(s[i], off);
    }
    __shared__ double red[4][8];
    int w = threadIdx.x >> 6, lane = threadIdx.x & 63;
    if (lane == 0) {
#pragma unroll
        for (int i = 0; i < 8; i++) red[w][i] = s[i];
    }
    __syncthreads();
    if (threadIdx.x == 0) {
#pragma unroll
        for (int i = 0; i < 8; i++) {
            double t = red[0][i] + red[1][i] + red[2][i] + red[3][i];
            atomicAdd(&ws[i], t);
        }
    }
}

// ---------------------------------------------------------------------------
// Fused kernel, 3 threads per node (768 threads / graph), role = tid/256
// (wave-uniform). Role r scans a third of the kNN range; roles 1,2 publish
// their top-3 (in (d,idx) order); role 0 merges by streaming insert — exact
// stable top-3 of the full ascending scan. Each role then computes ONE edge's
// MLP solo (round-8 verbatim solo path -> bit-identical per-edge values);
// partials summed in round-8 order ((e0+e1)+e2).
// amdgpu_waves_per_eu(6): VGPR cap ~85 -> 2 blocks/CU (24 waves), no spills.
// ---------------------------------------------------------------------------
__global__ __launch_bounds__(768)
__attribute__((amdgpu_waves_per_eu(6)))
void k_edgenet(
    const float*  __restrict__ x,
    const float*  __restrict__ gmm, const float* __restrict__ bta,
    const float*  __restrict__ ew1, const float* __restrict__ eb1,
    const float*  __restrict__ ew2, const float* __restrict__ eb2,
    const float*  __restrict__ ew3, const float* __restrict__ eb3,
    const float*  __restrict__ dw1, const float* __restrict__ db1,
    const float*  __restrict__ dw2, const float* __restrict__ db2,
    const float*  __restrict__ dw3, const float* __restrict__ db3,
    const double* __restrict__ bnstat,
    float*        __restrict__ out)
{
    __shared__ float4 s_h4[NN];       // normalized points
    __shared__ float  s_sq[NN];
    __shared__ float2 s_he2[NN];      // encoder outputs
    __shared__ float  s_sq2[NN];
    __shared__ float4 s_pd[2][NN];    // roles 1,2 published top-3 distances
    __shared__ int4   s_pi[2][NN];    // roles 1,2 published top-3 indices
    __shared__ int4   s_idx[NN];      // merged (i0,i1,i2)
    __shared__ float4 s_part[2][NN];  // roles 1,2 MLP partials

    const int tid  = threadIdx.x;
    const int n    = tid & (NN - 1);
    const int role = tid >> 8;        // 0,1,2 — wave-uniform
    const int b    = blockIdx.x;

    // BN parameters (uniform)
    const double cnt = (double)(NB * NN);
    float mu[NF], rstd[NF];
#pragma unroll
    for (int f = 0; f < NF; f++) {
        double m   = bnstat[f] / cnt;
        double var = bnstat[4 + f] / cnt - m * m;
        mu[f]   = (float)m;
        rstd[f] = 1.0f / sqrtf((float)var + BN_EPS);
    }

    if (role == 0) {
        float4 xv = ((const float4*)x)[b * NN + n];
        float t0 = (xv.x - mu[0]) * rstd[0] * gmm[0] + bta[0];
        float t1 = (xv.y - mu[1]) * rstd[1] * gmm[1] + bta[1];
        float t2 = (xv.z - mu[2]) * rstd[2] * gmm[2] + bta[2];
        float t3 = (xv.w - mu[3]) * rstd[3] * gmm[3] + bta[3];
        s_h4[n] = make_float4(t0, t1, t2, t3);
        s_sq[n] = t0 * t0 + t1 * t1 + t2 * t2 + t3 * t3;
    }
    __syncthreads();

    float4 hv = s_h4[n];
    float h0 = hv.x, h1 = hv.y, h2 = hv.z, h3 = hv.w;
    float sq = s_sq[n];

    // ---------------- encoder kNN: third-scan ------------------------------
    float d0 = FLT_BIG, d1 = FLT_BIG, d2 = FLT_BIG;
    int   i0 = 0, i1 = 0, i2 = 0;
    {
        const int mbeg = (role == 0) ? 0 : (role == 1 ? 86 : 171);
        const int mend = (role == 0) ? 86 : (role == 1 ? 171 : 256);
        for (int m = mbeg; m < mend; ++m) {
            float4 a = s_h4[m];
            float dot = h0 * a.x + h1 * a.y + h2 * a.z + h3 * a.w;
            float dd = (sq + s_sq[m]) - 2.0f * dot;
            KNN_UPDATE(dd, m);
        }
    }
    if (role != 0) {
        s_pd[role - 1][n] = make_float4(d0, d1, d2, 0.0f);
        s_pi[role - 1][n] = make_int4(i0, i1, i2, 0);
    }
    __syncthreads();
    if (role == 0) {
#pragma unroll
        for (int r = 0; r < 2; ++r) {
            float4 pd = s_pd[r][n]; int4 pi = s_pi[r][n];
            KNN_UPDATE(pd.x, pi.x);
            KNN_UPDATE(pd.y, pi.y);
            KNN_UPDATE(pd.z, pi.z);
        }
        s_idx[n] = make_int4(i0, i1, i2, 0);
    }
    __syncthreads();

    // ---------------- encoder MLP: one edge per role (solo, rnd-8 path) ----
    {
        int4 idx = s_idx[n];
        int j = (role == 0) ? idx.x : (role == 1 ? idx.y : idx.z);

        f32x16 Aa = ldw16(eb1), Ab = ldw16(eb1 + 16);
        ROW1(h0, ew1 + 0 * BIG, Aa, Ab);
        ROW1(h1, ew1 + 1 * BIG, Aa, Ab);
        ROW1(h2, ew1 + 2 * BIG, Aa, Ab);
        ROW1(h3, ew1 + 3 * BIG, Aa, Ab);
        float4 a2v = s_h4[j];
        float p20 = a2v.x - h0, p21 = a2v.y - h1;
        float p22 = a2v.z - h2, p23 = a2v.w - h3;
        ROW1(p20, ew1 + 4 * BIG, Aa, Ab);
        ROW1(p21, ew1 + 5 * BIG, Aa, Ab);
        ROW1(p22, ew1 + 6 * BIG, Aa, Ab);
        ROW1(p23, ew1 + 7 * BIG, Aa, Ab);
        Aa = relu16(Aa); Ab = relu16(Ab);

        float o0e2 = eb3[0], o1e2 = eb3[1];
        { L2S(ew2, eb2, 0,  Aa, Ab, QS0); L3ES(0,  QS0); }
        { L2S(ew2, eb2, 16, Aa, Ab, QS1); L3ES(16, QS1); }
        float r0 = fmaxf(o0e2, 0.0f), r1 = fmaxf(o1e2, 0.0f);
        if (role != 0) {
            s_part[role - 1][n] = make_float4(r0, r1, 0.0f, 0.0f);
        } else {
            s_pd[0][n] = make_float4(r0, r1, 0.0f, 0.0f);  // stash own partial
        }
    }
    __syncthreads();

    if (role == 0) {
        float4 me = s_pd[0][n];
        float4 p1 = s_part[0][n];
        float4 p2 = s_part[1][n];
        float ms0 = (me.x + p1.x) + p2.x;   // ((e0+e1)+e2) — round-8 order
        float ms1 = (me.y + p1.y) + p2.y;
        float he0 = ms0 / 3.0f, he1 = ms1 / 3.0f;
        s_he2[n] = make_float2(he0, he1);
        s_sq2[n] = he0 * he0 + he1 * he1;
    }
    __syncthreads();

    float2 hev = s_he2[n];
    float he0 = hev.x, he1 = hev.y;
    float sqe = s_sq2[n];

    // ---------------- decoder kNN: third-scan ------------------------------
    d0 = FLT_BIG; d1 = FLT_BIG; d2 = FLT_BIG;
    i0 = 0; i1 = 0; i2 = 0;
    {
        const int mbeg = (role == 0) ? 0 : (role == 1 ? 86 : 171);
        const int mend = (role == 0) ? 86 : (role == 1 ? 171 : 256);
        for (int m = mbeg; m < mend; ++m) {
            float2 a = s_he2[m];
            float dot = he0 * a.x + he1 * a.y;
            float dd = (sqe + s_sq2[m]) - 2.0f * dot;
            KNN_UPDATE(dd, m);
        }
    }
    if (role != 0) {
        s_pd[role - 1][n] = make_float4(d0, d1, d2, 0.0f);
        s_pi[role - 1][n] = make_int4(i0, i1, i2, 0);
    }
    __syncthreads();
    if (role == 0) {
#pragma unroll
        for (int r = 0; r < 2; ++r) {
            float4 pd = s_pd[r][n]; int4 pi = s_pi[r][n];
            KNN_UPDATE(pd.x, pi.x);
            KNN_UPDATE(pd.y, pi.y);
            KNN_UPDATE(pd.z, pi.z);
        }
        s_idx[n] = make_int4(i0, i1, i2, 0);
    }
    __syncthreads();

    // ---------------- decoder MLP: one edge per role (solo) ----------------
    {
        int4 idx = s_idx[n];
        int j = (role == 0) ? idx.x : (role == 1 ? idx.y : idx.z);

        f32x16 Ba = ldw16(db1), Bb = ldw16(db1 + 16);
        ROW1(he0, dw1 + 0 * BIG, Ba, Bb);
        ROW1(he1, dw1 + 1 * BIG, Ba, Bb);
        float2 a2v = s_he2[j];
        float p20 = a2v.x - he0, p21 = a2v.y - he1;
        ROW1(p20, dw1 + 2 * BIG, Ba, Bb);
        ROW1(p21, dw1 + 3 * BIG, Ba, Bb);
        Ba = relu16(Ba); Bb = relu16(Bb);

        f32x4v ove2 = ldw4(db3);
        { L2S(dw2, db2, 0,  Ba, Bb, QF0); L3DS(0,  QF0); }
        { L2S(dw2, db2, 16, Ba, Bb, QF1); L3DS(16, QF1); }
        if (role != 0) {
            s_part[role - 1][n] = make_float4(ove2[0], ove2[1], ove2[2], ove2[3]);
        } else {
            s_pd[0][n] = make_float4(ove2[0], ove2[1], ove2[2], ove2[3]);
        }
    }
    __syncthreads();

    if (role == 0) {
        float4 me = s_pd[0][n];
        float4 p1 = s_part[0][n];
        float4 p2 = s_part[1][n];
        float4 ov;                         // ((e0+e1)+e2) — round-8 order
        ov.x = ((me.x + p1.x) + p2.x) / 3.0f;
        ov.y = ((me.y + p1.y) + p2.y) / 3.0f;
        ov.z = ((me.z + p1.z) + p2.z) / 3.0f;
        ov.w = ((me.w + p1.w) + p2.w) / 3.0f;
        ((float4*)out)[b * NN + n] = ov;
    }
}

// ---------------------------------------------------------------------------
extern "C" void kernel_launch(void* const* d_in, const int* in_sizes, int n_in,
                              void* d_out, int out_size, void* d_ws, size_t ws_size,
                              hipStream_t stream) {
    const float* x   = (const float*)d_in[0];
    const float* gmm = (const float*)d_in[1];
    const float* bta = (const float*)d_in[2];
    const float* ew1 = (const float*)d_in[3];
    const float* eb1 = (const float*)d_in[4];
    const float* ew2 = (const float*)d_in[5];
    const float* eb2 = (const float*)d_in[6];
    const float* ew3 = (const float*)d_in[7];
    const float* eb3 = (const float*)d_in[8];
    const float* dw1 = (const float*)d_in[9];
    const float* db1 = (const float*)d_in[10];
    const float* dw2 = (const float*)d_in[11];
    const float* db2 = (const float*)d_in[12];
    const float* dw3 = (const float*)d_in[13];
    const float* db3 = (const float*)d_in[14];
    double* ws = (double*)d_ws;
    float* out = (float*)d_out;

    hipLaunchKernelGGL(k_zero_ws, dim3(1), dim3(64), 0, stream, ws);
    hipLaunchKernelGGL(k_bn_reduce, dim3(256), dim3(256), 0, stream,
                       (const float4*)x, ws);
    hipLaunchKernelGGL(k_edgenet, dim3(NB), dim3(768), 0, stream,
                       x, gmm, bta, ew1, eb1, ew2, eb2, ew3, eb3,
                       dw1, db1, dw2, db2, dw3, db3, ws, out);
}